// Round 1
// baseline (1033.003 us; speedup 1.0000x reference)
//
#include <hip/hip_runtime.h>
#include <cstdint>
#include <cmath>

// HashEncoderHyFluid round 6: bucket-LDS staging for scales 0..5.
// r5 analysis: gather is VMEM-request-throughput bound (~1.2 cyc/unique line
// per CU, ~204 req/query over 16 scales; HBM 19%, VALU 19% -> neither BW nor
// compute bound). Scales 0..5 have per-bucket corner footprints of <=500
// table entries (s=0: exactly 16). New bucket_kernel: one wave per Morton
// bucket stages the bbox of corner points into LDS once, then interpolates
// all ~15 bucket queries from LDS -> removes ~84 req/query (~40% of request
// budget) from the VMEM pipe, replacing it with ~20M staging requests plus
// LDS-pipe reads (idle pipe). gather_kernel keeps s=6..15 only.
// Pipeline: memset(hist,cur) -> histogram -> scan(1024t) -> scatter(perm,
// c_sorted) -> bucket_kernel(s0..5) -> gather(s6..15) -> direct transpose.

#define NSCALES 16
#define TPB 256
#define BINS 65536
#define WPB 4      // waves (=buckets) per block in bucket_kernel
#define SCAP 512   // max staged entries per bucket*scale (worst case 500 @s=5)
#define NSB 6      // scales 0..NSB-1 handled by bucket_kernel

struct Cfg {
  float    res[NSCALES][4];
  uint32_t key[NSCALES][4];
  uint32_t mask[NSCALES];
  int      offset[NSCALES];
  int      dense[NSCALES];
};

typedef float v4f __attribute__((ext_vector_type(4)));
typedef float v2f __attribute__((ext_vector_type(2)));

__device__ __forceinline__ uint32_t bucket_key(float x, float y, float z, float w)
{
  uint32_t bx = (uint32_t)(x * 16.f); bx = bx > 15u ? 15u : bx;
  uint32_t by = (uint32_t)(y * 16.f); by = by > 15u ? 15u : by;
  uint32_t bz = (uint32_t)(z * 16.f); bz = bz > 15u ? 15u : bz;
  uint32_t bt = (uint32_t)(w * 16.f); bt = bt > 15u ? 15u : bt;
  uint32_t k = 0;
#pragma unroll
  for (int b = 0; b < 4; ++b) {
    k |= ((bx >> b) & 1u) << (4 * b + 0);
    k |= ((by >> b) & 1u) << (4 * b + 1);
    k |= ((bz >> b) & 1u) << (4 * b + 2);
    k |= ((bt >> b) & 1u) << (4 * b + 3);
  }
  return k;
}

// ---------------- sort phase ----------------
__global__ __launch_bounds__(TPB) void hist_kernel(
    const float* __restrict__ xyzt, uint32_t* __restrict__ hist, int N)
{
  const int i = blockIdx.x * TPB + threadIdx.x;
  if (i >= N) return;
  const v4f c = *(reinterpret_cast<const v4f*>(xyzt) + i);
  atomicAdd(&hist[bucket_key(c.x, c.y, c.z, c.w)], 1u);
}

__global__ __launch_bounds__(1024) void scan_kernel(
    const uint32_t* __restrict__ hist, uint32_t* __restrict__ boff)
{
  __shared__ uint32_t part[1024];
  const int t = threadIdx.x;
  const int base = t * (BINS / 1024);
  uint32_t s = 0;
  for (int j = 0; j < BINS / 1024; ++j) s += hist[base + j];
  part[t] = s;
  __syncthreads();
  for (int off = 1; off < 1024; off <<= 1) {
    uint32_t v = (t >= off) ? part[t - off] : 0u;
    __syncthreads();
    part[t] += v;
    __syncthreads();
  }
  uint32_t run = part[t] - s;   // exclusive prefix of this chunk
  for (int j = 0; j < BINS / 1024; ++j) {
    boff[base + j] = run;
    run += hist[base + j];
  }
}

__global__ __launch_bounds__(TPB) void scatter_kernel(
    const float* __restrict__ xyzt,
    const uint32_t* __restrict__ boff, uint32_t* __restrict__ cur,
    uint32_t* __restrict__ perm, float* __restrict__ c_sorted, int N)
{
  const int i = blockIdx.x * TPB + threadIdx.x;
  if (i >= N) return;
  const v4f c = *(reinterpret_cast<const v4f*>(xyzt) + i);
  const uint32_t k = bucket_key(c.x, c.y, c.z, c.w);
  const uint32_t pos = boff[k] + atomicAdd(&cur[k], 1u);
  perm[pos] = (uint32_t)i;
  *(reinterpret_cast<v4f*>(c_sorted) + pos) = c;
}

// ---------------- bucket-LDS kernel: scales 0..NSB-1 ----------------
// One wave per Morton bucket. Per scale: stage the bucket's corner-point
// bbox (<=SCAP float2 entries) into LDS, then interpolate all bucket
// queries from LDS. Per-query range guard (float rounding at bucket edges)
// falls back to the generic global path (~never taken).
__global__ __launch_bounds__(TPB) void bucket_kernel(
    const float*    __restrict__ coords,
    const float*    __restrict__ table,
    const uint32_t* __restrict__ hist,
    const uint32_t* __restrict__ boff,
    float2*         __restrict__ ws,
    int N, Cfg cfg)
{
  __shared__ float2 S[WPB][SCAP];
  const int wave = threadIdx.x >> 6;
  const int lane = threadIdx.x & 63;
  const uint32_t k = (uint32_t)blockIdx.x * WPB + (uint32_t)wave;

  // Morton decode: bit (4b+d) of k is bit b of dim-d bucket coord
  int bc[4];
#pragma unroll
  for (int d = 0; d < 4; ++d) {
    uint32_t v = 0;
#pragma unroll
    for (int b = 0; b < 4; ++b) v |= ((k >> (4 * b + d)) & 1u) << b;
    bc[d] = (int)v;
  }
  const uint32_t cnt   = hist[k];
  const uint32_t start = boff[k];

#pragma unroll 1
  for (int s = 0; s < NSB; ++s) {
    const float rx = cfg.res[s][0], ry = cfg.res[s][1];
    const float rz = cfg.res[s][2], rw = cfg.res[s][3];
    const uint32_t K0 = cfg.key[s][0], K1 = cfg.key[s][1];
    const uint32_t K2 = cfg.key[s][2], K3 = cfg.key[s][3];
    const uint32_t msk = cfg.mask[s];
    const int dense = cfg.dense[s];
    const float2* __restrict__ tb =
        reinterpret_cast<const float2*>(table + cfg.offset[s]);

    // corner-point bbox of this bucket at scale s
    int plo[4], pc[4];
#pragma unroll
    for (int d = 0; d < 4; ++d) {
      const int R  = (int)cfg.res[s][d];
      const int lo = (bc[d] * R) >> 4;                 // min floor(x*R)
      const int hi = ((bc[d] + 1) * R - 1) >> 4;       // max floor(x*R)
      plo[d] = lo;
      pc[d]  = hi - lo + 2;                            // corner points
    }
    const int pcx = pc[0], pcy = pc[1], pcz = pc[2];
    const int tot = pcx * pcy * pcz * pc[3];
    const bool staged = (tot <= SCAP);

    if (staged) {
      for (int e = lane; e < tot; e += 64) {
        int t = e;
        const int ex = t % pcx; t /= pcx;
        const int ey = t % pcy; t /= pcy;
        const int ez = t % pcz; t /= pcz;
        const int ew = t;
        const uint32_t X = (uint32_t)(plo[0] + ex) * K0;
        const uint32_t Y = (uint32_t)(plo[1] + ey) * K1;
        const uint32_t Z = (uint32_t)(plo[2] + ez) * K2;
        const uint32_t W = (uint32_t)(plo[3] + ew) * K3;
        const uint32_t idx = dense ? (X + Y + Z + W)
                                   : ((X ^ Y ^ Z ^ W) & msk);
        S[wave][e] = tb[idx];
      }
    }
    __syncthreads();   // uniform: every thread, every scale iteration

    for (uint32_t base = 0; base < cnt; base += 64u) {
      const uint32_t qi = base + (uint32_t)lane;
      if (qi < cnt) {
        const int q = (int)(start + qi);
        const v4f c = *(reinterpret_cast<const v4f*>(coords) + q);
        const float px = c.x * rx, py = c.y * ry, pz = c.z * rz, pw = c.w * rw;
        const float gx = floorf(px), gy = floorf(py);
        const float gz = floorf(pz), gw = floorf(pw);
        const float fx = px - gx, fy = py - gy, fz = pz - gz, fw = pw - gw;
        const int ix = (int)gx, iy = (int)gy, iz = (int)gz, iw = (int)gw;
        const float wx0 = 1.f - fx, wy0 = 1.f - fy;
        const float wz0 = 1.f - fz, ww0 = 1.f - fw;

        const int lx = ix - plo[0], ly = iy - plo[1];
        const int lz = iz - plo[2], lw = iw - plo[3];
        const bool ok = staged &&
            (unsigned)lx <= (unsigned)(pcx - 2) &&
            (unsigned)ly <= (unsigned)(pcy - 2) &&
            (unsigned)lz <= (unsigned)(pcz - 2) &&
            (unsigned)lw <= (unsigned)(pc[3] - 2);

        float a0 = 0.f, a1 = 0.f;
        if (ok) {
          const float wyv[2] = { wy0, fy };
          const float wzv[2] = { wz0, fz };
          const float wwv[2] = { ww0, fw };
          const int b0 = lx + pcx * (ly + pcy * (lz + pcz * lw));
#pragma unroll
          for (int jw = 0; jw < 2; ++jw)
#pragma unroll
            for (int jz = 0; jz < 2; ++jz)
#pragma unroll
              for (int jy = 0; jy < 2; ++jy) {
                const int o = b0 + pcx * (jy + pcy * (jz + pcz * jw));
                const float2 v0 = S[wave][o];       // x-corner 0
                const float2 v1 = S[wave][o + 1];   // x-corner 1 (adjacent)
                const float wv = wyv[jy] * wzv[jz] * wwv[jw];
                a0 = fmaf(wv, fmaf(wx0, v0.x, fx * v1.x), a0);
                a1 = fmaf(wv, fmaf(wx0, v0.y, fx * v1.y), a1);
              }
        } else {
          // rare edge fallback: generic 16 global loads
          const uint32_t X0 = (uint32_t)ix * K0, X1 = X0 + K0;
          const uint32_t Y0 = (uint32_t)iy * K1, Y1 = Y0 + K1;
          const uint32_t Z0 = (uint32_t)iz * K2, Z1 = Z0 + K2;
          const uint32_t U0 = (uint32_t)iw * K3, U1 = U0 + K3;
          const float wAv[4] = { wx0 * wy0, fx * wy0, wx0 * fy, fx * fy };
          const float wBv[4] = { wz0 * ww0, fz * ww0, wz0 * fw, fz * fw };
          uint32_t hA[4], hB[4];
          if (dense) {
            hA[0] = X0 + Y0; hA[1] = X1 + Y0; hA[2] = X0 + Y1; hA[3] = X1 + Y1;
            hB[0] = Z0 + U0; hB[1] = Z1 + U0; hB[2] = Z0 + U1; hB[3] = Z1 + U1;
#pragma unroll
            for (int i = 0; i < 16; ++i) {
              const uint32_t idx = hA[i & 3] + hB[i >> 2];
              const float2 v = tb[idx];
              const float w = wAv[i & 3] * wBv[i >> 2];
              a0 = fmaf(w, v.x, a0); a1 = fmaf(w, v.y, a1);
            }
          } else {
            hA[0] = X0 ^ Y0; hA[1] = X1 ^ Y0; hA[2] = X0 ^ Y1; hA[3] = X1 ^ Y1;
            hB[0] = Z0 ^ U0; hB[1] = Z1 ^ U0; hB[2] = Z0 ^ U1; hB[3] = Z1 ^ U1;
#pragma unroll
            for (int i = 0; i < 16; ++i) {
              const uint32_t idx = (hA[i & 3] ^ hB[i >> 2]) & msk;
              const float2 v = tb[idx];
              const float w = wAv[i & 3] * wBv[i >> 2];
              a0 = fmaf(w, v.x, a0); a1 = fmaf(w, v.y, a1);
            }
          }
        }
        v2f val = { a0, a1 };
        __builtin_nontemporal_store(val, (v2f*)&ws[(size_t)s * N + q]);
      }
    }
    __syncthreads();   // uniform: protect LDS reuse by next scale
  }
}

// ---------------- gather: per-scale (s >= s_base), scale = slow grid dim ----
__global__ __launch_bounds__(TPB) void gather_kernel(
    const float*  __restrict__ coords,
    const float*  __restrict__ table,
    float2*       __restrict__ ws,
    int N, int s_base, Cfg cfg)
{
  const int s = (int)blockIdx.y + s_base;
  const int q = blockIdx.x * TPB + threadIdx.x;
  if (q >= N) return;
  const v4f c = *(reinterpret_cast<const v4f*>(coords) + q);

  const float rx = cfg.res[s][0], ry = cfg.res[s][1];
  const float rz = cfg.res[s][2], rw = cfg.res[s][3];
  const uint32_t K0 = cfg.key[s][0], K1 = cfg.key[s][1];
  const uint32_t K2 = cfg.key[s][2], K3 = cfg.key[s][3];

  const float px = c.x * rx, py = c.y * ry, pz = c.z * rz, pw = c.w * rw;
  const float gx = floorf(px), gy = floorf(py), gz = floorf(pz), gw = floorf(pw);
  const float fx = px - gx, fy = py - gy, fz = pz - gz, fw = pw - gw;
  const uint32_t ix = (uint32_t)(int)gx, iy = (uint32_t)(int)gy;
  const uint32_t iz = (uint32_t)(int)gz, iw = (uint32_t)(int)gw;

  const uint32_t x0 = ix * K0, x1 = x0 + K0;
  const uint32_t y0 = iy * K1, y1 = y0 + K1;
  const uint32_t z0 = iz * K2, z1 = z0 + K2;
  const uint32_t u0 = iw * K3, u1 = u0 + K3;

  const float wx0 = 1.f - fx, wy0 = 1.f - fy, wz0 = 1.f - fz, ww0 = 1.f - fw;
  const float wA[4] = { wx0 * wy0, fx * wy0, wx0 * fy, fx * fy };
  const float wB[4] = { wz0 * ww0, fz * ww0, wz0 * fw, fz * fw };

  const float*  tbf = table + cfg.offset[s];
  const float2* __restrict__ tb  = reinterpret_cast<const float2*>(tbf);
  const float4* __restrict__ tb4 = reinterpret_cast<const float4*>(tbf);

  float a0 = 0.f, a1 = 0.f;
  if (cfg.dense[s]) {
    const uint32_t hA[4] = { x0 + y0, x1 + y0, x0 + y1, x1 + y1 };
    const uint32_t hB[4] = { z0 + u0, z1 + u0, z0 + u1, z1 + u1 };
#pragma unroll
    for (int i = 0; i < 16; ++i) {
      const uint32_t idx = hA[i & 3] + hB[i >> 2];
      const float2 v = tb[idx];
      const float w = wA[i & 3] * wB[i >> 2];
      a0 = fmaf(w, v.x, a0);
      a1 = fmaf(w, v.y, a1);
    }
  } else {
    const uint32_t msk = cfg.mask[s];
    if ((ix & 1u) == 0u) {
      // even ix: x-corner pair = {p, p^1} -> one aligned float4 each
      const uint32_t yv[2] = { y0, y1 };
      const uint32_t zw[4] = { z0 ^ u0, z1 ^ u0, z0 ^ u1, z1 ^ u1 };
#pragma unroll
      for (int j = 0; j < 8; ++j) {
        const int jy = j & 1, jz = j >> 1;
        const uint32_t p  = (x0 ^ yv[jy] ^ zw[jz]) & msk;
        const uint32_t e  = p & ~1u;
        const uint32_t sel = p & 1u;
        const float4 v = tb4[e >> 1];
        const float wlo = wA[2 * jy]     * wB[jz];
        const float whi = wA[2 * jy + 1] * wB[jz];
        const float l0 = sel ? v.z : v.x, l1 = sel ? v.w : v.y;
        const float h0 = sel ? v.x : v.z, h1 = sel ? v.y : v.w;
        a0 = fmaf(wlo, l0, fmaf(whi, h0, a0));
        a1 = fmaf(wlo, l1, fmaf(whi, h1, a1));
      }
    } else {
      const uint32_t hA[4] = { x0 ^ y0, x1 ^ y0, x0 ^ y1, x1 ^ y1 };
      const uint32_t hB[4] = { z0 ^ u0, z1 ^ u0, z0 ^ u1, z1 ^ u1 };
#pragma unroll
      for (int i = 0; i < 16; ++i) {
        const uint32_t idx = (hA[i & 3] ^ hB[i >> 2]) & msk;
        const float2 v = tb[idx];
        const float w = wA[i & 3] * wB[i >> 2];
        a0 = fmaf(w, v.x, a0);
        a1 = fmaf(w, v.y, a1);
      }
    }
  }
  v2f val = { a0, a1 };
  __builtin_nontemporal_store(val, (v2f*)&ws[(size_t)s * N + q]);
}

// ---------------- direct transpose + perm scatter ----------------
// thread = one float4 of output (2 scales x 2 feats for one query)
__global__ __launch_bounds__(TPB) void transpose_direct(
    const float2*   __restrict__ ws,
    const uint32_t* __restrict__ perm,
    float*          __restrict__ out,
    int N)
{
  const int g = blockIdx.x * TPB + threadIdx.x;
  if (g >= N * 8) return;
  const int q  = g >> 3;
  const int l8 = g & 7;
  const int s0 = l8 * 2;
  const float2 a = ws[(size_t)s0 * N + q];
  const float2 b = ws[(size_t)(s0 + 1) * N + q];
  const uint32_t pq = perm[q];
  v4f val = { a.x, a.y, b.x, b.y };
  __builtin_nontemporal_store(val, (v4f*)(out + (size_t)pq * 32 + l8 * 4));
}

// ---------------- fallback phase-2: LDS transpose (no perm) ----------------
__global__ __launch_bounds__(TPB) void transpose_kernel(
    const float2* __restrict__ ws,
    float*        __restrict__ out,
    int N)
{
  __shared__ float2 st[NSCALES][TPB + 1];
  const int t  = threadIdx.x;
  const int q  = blockIdx.x * TPB + t;
  const int ql = q < N ? q : N - 1;
#pragma unroll
  for (int s = 0; s < NSCALES; ++s)
    st[s][t] = ws[(size_t)s * N + ql];
  __syncthreads();
  const int base = blockIdx.x * (TPB * 2 * NSCALES);
#pragma unroll
  for (int it = 0; it < 8; ++it) {
    const int G  = it * 1024 + t * 4;
    const int qi = G >> 5;
    const int s0 = (G & 31) >> 1;
    if (blockIdx.x * TPB + qi < N) {
      const float2 a = st[s0][qi];
      const float2 b = st[s0 + 1][qi];
      v4f val = { a.x, a.y, b.x, b.y };
      __builtin_nontemporal_store(val, (v4f*)(out + base + G));
    }
  }
}

// ---------------- fallback: fused single-kernel (if ws tiny) ----------------
__global__ __launch_bounds__(TPB) void hashenc_fused(
    const float4* __restrict__ xyzt,
    const float*  __restrict__ table,
    float*        __restrict__ out,
    int N, Cfg cfg)
{
  __shared__ float2 st[NSCALES][TPB + 1];
  const int t  = threadIdx.x;
  const int q  = blockIdx.x * TPB + t;
  const int ql = q < N ? q : N - 1;
  const float4 c = xyzt[ql];
#pragma unroll 1
  for (int s = 0; s < NSCALES; ++s) {
    const float rx = cfg.res[s][0], ry = cfg.res[s][1];
    const float rz = cfg.res[s][2], rw = cfg.res[s][3];
    const uint32_t K0 = cfg.key[s][0], K1 = cfg.key[s][1];
    const uint32_t K2 = cfg.key[s][2], K3 = cfg.key[s][3];
    const float px = c.x * rx, py = c.y * ry, pz = c.z * rz, pw = c.w * rw;
    const float gx = floorf(px), gy = floorf(py), gz = floorf(pz), gw = floorf(pw);
    const float fx = px - gx, fy = py - gy, fz = pz - gz, fw = pw - gw;
    const uint32_t ix = (uint32_t)(int)gx, iy = (uint32_t)(int)gy;
    const uint32_t iz = (uint32_t)(int)gz, iw = (uint32_t)(int)gw;
    const uint32_t x0 = ix * K0, x1 = x0 + K0;
    const uint32_t y0 = iy * K1, y1 = y0 + K1;
    const uint32_t z0 = iz * K2, z1 = z0 + K2;
    const uint32_t u0 = iw * K3, u1 = u0 + K3;
    const float wx0 = 1.f - fx, wy0 = 1.f - fy, wz0 = 1.f - fz, ww0 = 1.f - fw;
    const float wA[4] = { wx0 * wy0, fx * wy0, wx0 * fy, fx * fy };
    const float wB[4] = { wz0 * ww0, fz * ww0, wz0 * fw, fz * fw };
    const float2* __restrict__ tb =
        reinterpret_cast<const float2*>(table + cfg.offset[s]);
    float a0 = 0.f, a1 = 0.f;
    if (cfg.dense[s]) {
      const uint32_t hA[4] = { x0 + y0, x1 + y0, x0 + y1, x1 + y1 };
      const uint32_t hB[4] = { z0 + u0, z1 + u0, z0 + u1, z1 + u1 };
#pragma unroll
      for (int i = 0; i < 16; ++i) {
        const uint32_t idx = hA[i & 3] + hB[i >> 2];
        const float2 v = tb[idx];
        const float w = wA[i & 3] * wB[i >> 2];
        a0 = fmaf(w, v.x, a0); a1 = fmaf(w, v.y, a1);
      }
    } else {
      const uint32_t msk = cfg.mask[s];
      const uint32_t hA[4] = { x0 ^ y0, x1 ^ y0, x0 ^ y1, x1 ^ y1 };
      const uint32_t hB[4] = { z0 ^ u0, z1 ^ u0, z0 ^ u1, z1 ^ u1 };
#pragma unroll
      for (int i = 0; i < 16; ++i) {
        const uint32_t idx = (hA[i & 3] ^ hB[i >> 2]) & msk;
        const float2 v = tb[idx];
        const float w = wA[i & 3] * wB[i >> 2];
        a0 = fmaf(w, v.x, a0); a1 = fmaf(w, v.y, a1);
      }
    }
    st[s][t] = make_float2(a0, a1);
  }
  __syncthreads();
  const int base = blockIdx.x * (TPB * 2 * NSCALES);
#pragma unroll
  for (int it = 0; it < 8; ++it) {
    const int G  = it * 1024 + t * 4;
    const int qi = G >> 5;
    const int s0 = (G & 31) >> 1;
    if (blockIdx.x * TPB + qi < N) {
      const float2 a = st[s0][qi];
      const float2 b = st[s0 + 1][qi];
      v4f val = { a.x, a.y, b.x, b.y };
      __builtin_nontemporal_store(val, (v4f*)(out + base + G));
    }
  }
}

// ---- host-side config, bit-exact replication of build_config() ----
static void build_cfg(Cfg& cfg)
{
  const double minr[4] = { 16.0, 16.0, 16.0, 16.0 };
  const double maxr[4] = { 256.0, 256.0, 256.0, 128.0 };
  const uint32_t primes[4] = { 1u, 2654435761u, 805459861u, 3674653429u };

  double b[4];
  for (int d = 0; d < 4; ++d)
    b[d] = ::exp((::log(maxr[d]) - ::log(minr[d])) / (double)(NSCALES - 1));

  long long total = 0;
  for (int s = 0; s < NSCALES; ++s) {
    long long res[4];
    for (int d = 0; d < 4; ++d)
      res[d] = (long long)::ceil(minr[d] * ::pow(b[d], (double)s));

    const long long raw =
        (res[0] + 1) * (res[1] + 1) * (res[2] + 1) * (res[3] + 1);
    long long p = (raw % 8 == 0) ? raw : ((raw + 7) / 8) * 8;
    if (p > 524288) p = 524288;
    const int ind = (raw <= p) ? 1 : 0;

    for (int d = 0; d < 4; ++d) cfg.res[s][d] = (float)res[d];
    if (ind) {
      cfg.key[s][0] = 1u;
      cfg.key[s][1] = (uint32_t)(res[0] + 1);
      cfg.key[s][2] = (uint32_t)((res[0] + 1) * (res[1] + 1));
      cfg.key[s][3] = (uint32_t)((res[0] + 1) * (res[1] + 1) * (res[2] + 1));
    } else {
      for (int d = 0; d < 4; ++d) cfg.key[s][d] = primes[d];
    }
    cfg.mask[s]   = (uint32_t)(p - 1);
    cfg.offset[s] = (int)total;
    cfg.dense[s]  = ind;
    total += p * 2;
  }
}

static inline size_t align_up(size_t v, size_t a) { return (v + a - 1) & ~(a - 1); }

extern "C" void kernel_launch(void* const* d_in, const int* in_sizes, int n_in,
                              void* d_out, int out_size, void* d_ws, size_t ws_size,
                              hipStream_t stream)
{
  const float* xyzt  = (const float*)d_in[0];
  const float* table = (const float*)d_in[1];
  float*       out   = (float*)d_out;
  const int N = in_sizes[0] / 4;

  Cfg cfg;
  build_cfg(cfg);

  const int qblocks = (N + TPB - 1) / TPB;

  // workspace layout
  size_t off = 0;
  const size_t perm_off = off;             off = align_up(off + (size_t)N * 4, 256);
  const size_t hist_off = off;             off = align_up(off + (size_t)BINS * 4, 256);
  const size_t cur_off  = off;             off = align_up(off + (size_t)BINS * 4, 256);
  const size_t boff_off = off;             off = align_up(off + (size_t)BINS * 4, 256);
  const size_t cs_off   = align_up(off, 16);  off = cs_off + (size_t)N * 16;
  const size_t ws_off   = align_up(off, 16);
  const size_t need_sorted = ws_off + (size_t)N * NSCALES * sizeof(float2);
  const size_t need_plain  = (size_t)N * NSCALES * sizeof(float2);

  char* wsb = (char*)d_ws;

  if (ws_size >= need_sorted) {
    uint32_t* perm = (uint32_t*)(wsb + perm_off);
    uint32_t* hist = (uint32_t*)(wsb + hist_off);
    uint32_t* cur  = (uint32_t*)(wsb + cur_off);
    uint32_t* boff = (uint32_t*)(wsb + boff_off);
    float*    csrt = (float*)(wsb + cs_off);
    float2*   ws   = (float2*)(wsb + ws_off);

    hipMemsetAsync(hist, 0, (size_t)BINS * 4, stream);
    hipMemsetAsync(cur,  0, (size_t)BINS * 4, stream);
    hipLaunchKernelGGL(hist_kernel, dim3(qblocks), dim3(TPB), 0, stream,
                       xyzt, hist, N);
    hipLaunchKernelGGL(scan_kernel, dim3(1), dim3(1024), 0, stream, hist, boff);
    hipLaunchKernelGGL(scatter_kernel, dim3(qblocks), dim3(TPB), 0, stream,
                       xyzt, boff, cur, perm, csrt, N);
    // scales 0..NSB-1: per-bucket LDS staging (one wave per bucket)
    hipLaunchKernelGGL(bucket_kernel, dim3(BINS / WPB), dim3(TPB), 0, stream,
                       csrt, table, hist, boff, ws, N, cfg);
    // scales NSB..15: per-query VMEM gather
    hipLaunchKernelGGL(gather_kernel, dim3(qblocks, NSCALES - NSB), dim3(TPB),
                       0, stream, csrt, table, ws, N, NSB, cfg);
    const int tblocks = (N * 8 + TPB - 1) / TPB;
    hipLaunchKernelGGL(transpose_direct, dim3(tblocks), dim3(TPB), 0, stream,
                       ws, perm, out, N);
  } else if (ws_size >= need_plain) {
    float2* ws = (float2*)d_ws;
    hipLaunchKernelGGL(gather_kernel, dim3(qblocks, NSCALES), dim3(TPB), 0,
                       stream, xyzt, table, ws, N, 0, cfg);
    hipLaunchKernelGGL(transpose_kernel, dim3(qblocks), dim3(TPB), 0,
                       stream, ws, out, N);
  } else {
    hipLaunchKernelGGL(hashenc_fused, dim3(qblocks), dim3(TPB), 0,
                       stream, (const float4*)xyzt, table, out, N, cfg);
  }
}

// Round 2
// 811.239 us; speedup vs baseline: 1.2734x; 1.2734x over previous
//
#include <hip/hip_runtime.h>
#include <cstdint>
#include <cmath>

// HashEncoderHyFluid round 7: revert bucket split (r6 regression: staging
// requests ~62M + 15/64-lane interp made bucket_kernel ~290us vs ~100us it
// saved; small-scale per-query reads were L2-hot and cheap). gather is at
// ~1.5 cyc per unique-line request (~16 req/cyc/XCD L2 ceiling); attack
// stalls via MLP restructure: per scale, compute ALL corner indices ->
// issue ALL loads -> FMA (VGPR 36 -> ~70, 8-16 reqs in flight per wave).
// transpose_direct's scattered ws reads (16M random 8B) replaced by
// LDS-staged transpose: coalesced ws reads + same coalesced 128B/query
// permuted writes. ws stores no longer nontemporal (let L3 keep ws for the
// transpose read-back). memsets merged.
// Pipeline: memset(hist+cur) -> histogram -> scan -> scatter(perm,c_sorted)
//        -> gather16 (sorted coords, scale-major grid) -> LDS transpose+perm.

#define NSCALES 16
#define TPB 256
#define BINS 65536
#define QPB 128   // queries per transpose block

struct Cfg {
  float    res[NSCALES][4];
  uint32_t key[NSCALES][4];
  uint32_t mask[NSCALES];
  int      offset[NSCALES];
  int      dense[NSCALES];
};

typedef float v4f __attribute__((ext_vector_type(4)));
typedef float v2f __attribute__((ext_vector_type(2)));

__device__ __forceinline__ uint32_t bucket_key(float x, float y, float z, float w)
{
  uint32_t bx = (uint32_t)(x * 16.f); bx = bx > 15u ? 15u : bx;
  uint32_t by = (uint32_t)(y * 16.f); by = by > 15u ? 15u : by;
  uint32_t bz = (uint32_t)(z * 16.f); bz = bz > 15u ? 15u : bz;
  uint32_t bt = (uint32_t)(w * 16.f); bt = bt > 15u ? 15u : bt;
  uint32_t k = 0;
#pragma unroll
  for (int b = 0; b < 4; ++b) {
    k |= ((bx >> b) & 1u) << (4 * b + 0);
    k |= ((by >> b) & 1u) << (4 * b + 1);
    k |= ((bz >> b) & 1u) << (4 * b + 2);
    k |= ((bt >> b) & 1u) << (4 * b + 3);
  }
  return k;
}

// ---------------- sort phase ----------------
__global__ __launch_bounds__(TPB) void hist_kernel(
    const float* __restrict__ xyzt, uint32_t* __restrict__ hist, int N)
{
  const int i = blockIdx.x * TPB + threadIdx.x;
  if (i >= N) return;
  const v4f c = *(reinterpret_cast<const v4f*>(xyzt) + i);
  atomicAdd(&hist[bucket_key(c.x, c.y, c.z, c.w)], 1u);
}

__global__ __launch_bounds__(1024) void scan_kernel(
    const uint32_t* __restrict__ hist, uint32_t* __restrict__ boff)
{
  __shared__ uint32_t part[1024];
  const int t = threadIdx.x;
  const int base = t * (BINS / 1024);
  uint32_t s = 0;
  for (int j = 0; j < BINS / 1024; ++j) s += hist[base + j];
  part[t] = s;
  __syncthreads();
  for (int off = 1; off < 1024; off <<= 1) {
    uint32_t v = (t >= off) ? part[t - off] : 0u;
    __syncthreads();
    part[t] += v;
    __syncthreads();
  }
  uint32_t run = part[t] - s;   // exclusive prefix of this chunk
  for (int j = 0; j < BINS / 1024; ++j) {
    boff[base + j] = run;
    run += hist[base + j];
  }
}

__global__ __launch_bounds__(TPB) void scatter_kernel(
    const float* __restrict__ xyzt,
    const uint32_t* __restrict__ boff, uint32_t* __restrict__ cur,
    uint32_t* __restrict__ perm, float* __restrict__ c_sorted, int N)
{
  const int i = blockIdx.x * TPB + threadIdx.x;
  if (i >= N) return;
  const v4f c = *(reinterpret_cast<const v4f*>(xyzt) + i);
  const uint32_t k = bucket_key(c.x, c.y, c.z, c.w);
  const uint32_t pos = boff[k] + atomicAdd(&cur[k], 1u);
  perm[pos] = (uint32_t)i;
  *(reinterpret_cast<v4f*>(c_sorted) + pos) = c;
}

// ---------------- gather: per-scale, scale = slow grid dim ----------------
// MLP-restructured: per scale, compute all corner indices, issue all loads,
// then FMA. Keeps 8-16 requests in flight per wave instead of ~4.
__global__ __launch_bounds__(TPB) void gather_kernel(
    const float*  __restrict__ coords,
    const float*  __restrict__ table,
    float2*       __restrict__ ws,
    int N, int s_base, Cfg cfg)
{
  const int s = (int)blockIdx.y + s_base;
  const int q = blockIdx.x * TPB + threadIdx.x;
  if (q >= N) return;
  const v4f c = *(reinterpret_cast<const v4f*>(coords) + q);

  const float rx = cfg.res[s][0], ry = cfg.res[s][1];
  const float rz = cfg.res[s][2], rw = cfg.res[s][3];
  const uint32_t K0 = cfg.key[s][0], K1 = cfg.key[s][1];
  const uint32_t K2 = cfg.key[s][2], K3 = cfg.key[s][3];

  const float px = c.x * rx, py = c.y * ry, pz = c.z * rz, pw = c.w * rw;
  const float gx = floorf(px), gy = floorf(py), gz = floorf(pz), gw = floorf(pw);
  const float fx = px - gx, fy = py - gy, fz = pz - gz, fw = pw - gw;
  const uint32_t ix = (uint32_t)(int)gx, iy = (uint32_t)(int)gy;
  const uint32_t iz = (uint32_t)(int)gz, iw = (uint32_t)(int)gw;

  const uint32_t x0 = ix * K0, x1 = x0 + K0;
  const uint32_t y0 = iy * K1, y1 = y0 + K1;
  const uint32_t z0 = iz * K2, z1 = z0 + K2;
  const uint32_t u0 = iw * K3, u1 = u0 + K3;

  const float wx0 = 1.f - fx, wy0 = 1.f - fy, wz0 = 1.f - fz, ww0 = 1.f - fw;
  const float wA[4] = { wx0 * wy0, fx * wy0, wx0 * fy, fx * fy };
  const float wB[4] = { wz0 * ww0, fz * ww0, wz0 * fw, fz * fw };

  const float*  tbf = table + cfg.offset[s];
  const float2* __restrict__ tb  = reinterpret_cast<const float2*>(tbf);
  const float4* __restrict__ tb4 = reinterpret_cast<const float4*>(tbf);

  float a0 = 0.f, a1 = 0.f;
  if (cfg.dense[s]) {
    const uint32_t hA[4] = { x0 + y0, x1 + y0, x0 + y1, x1 + y1 };
    const uint32_t hB[4] = { z0 + u0, z1 + u0, z0 + u1, z1 + u1 };
    uint32_t idx[16];
#pragma unroll
    for (int i = 0; i < 16; ++i) idx[i] = hA[i & 3] + hB[i >> 2];
    float2 v[16];
#pragma unroll
    for (int i = 0; i < 16; ++i) v[i] = tb[idx[i]];
#pragma unroll
    for (int i = 0; i < 16; ++i) {
      const float w = wA[i & 3] * wB[i >> 2];
      a0 = fmaf(w, v[i].x, a0);
      a1 = fmaf(w, v[i].y, a1);
    }
  } else {
    const uint32_t msk = cfg.mask[s];
    if ((ix & 1u) == 0u) {
      // even ix: x-corner pair = {p, p^1} -> one aligned float4 each
      const uint32_t yv[2] = { y0, y1 };
      const uint32_t zw[4] = { z0 ^ u0, z1 ^ u0, z0 ^ u1, z1 ^ u1 };
      uint32_t p[8];
#pragma unroll
      for (int j = 0; j < 8; ++j)
        p[j] = (x0 ^ yv[j & 1] ^ zw[j >> 1]) & msk;
      float4 v[8];
#pragma unroll
      for (int j = 0; j < 8; ++j) v[j] = tb4[p[j] >> 1];
#pragma unroll
      for (int j = 0; j < 8; ++j) {
        const int jy = j & 1, jz = j >> 1;
        const uint32_t sel = p[j] & 1u;
        const float wlo = wA[2 * jy]     * wB[jz];
        const float whi = wA[2 * jy + 1] * wB[jz];
        const float l0 = sel ? v[j].z : v[j].x, l1 = sel ? v[j].w : v[j].y;
        const float h0 = sel ? v[j].x : v[j].z, h1 = sel ? v[j].y : v[j].w;
        a0 = fmaf(wlo, l0, fmaf(whi, h0, a0));
        a1 = fmaf(wlo, l1, fmaf(whi, h1, a1));
      }
    } else {
      const uint32_t hA[4] = { x0 ^ y0, x1 ^ y0, x0 ^ y1, x1 ^ y1 };
      const uint32_t hB[4] = { z0 ^ u0, z1 ^ u0, z0 ^ u1, z1 ^ u1 };
      uint32_t idx[16];
#pragma unroll
      for (int i = 0; i < 16; ++i) idx[i] = (hA[i & 3] ^ hB[i >> 2]) & msk;
      float2 v[16];
#pragma unroll
      for (int i = 0; i < 16; ++i) v[i] = tb[idx[i]];
#pragma unroll
      for (int i = 0; i < 16; ++i) {
        const float w = wA[i & 3] * wB[i >> 2];
        a0 = fmaf(w, v[i].x, a0);
        a1 = fmaf(w, v[i].y, a1);
      }
    }
  }
  // plain store (not nontemporal): let ws spill into L3 for the transpose
  ws[(size_t)s * N + q] = make_float2(a0, a1);
}

// ---------------- LDS transpose + perm scatter ----------------
// block = QPB sorted queries. Stage ws coalesced per scale into LDS, then
// 8 lanes emit one query's 128B output chunk (coalesced random-base write).
__global__ __launch_bounds__(TPB) void transpose_perm(
    const float2*   __restrict__ ws,
    const uint32_t* __restrict__ perm,
    float*          __restrict__ out,
    int N)
{
  __shared__ float2 st[NSCALES][QPB + 1];
  const int t  = threadIdx.x;
  const int q0 = blockIdx.x * QPB;
#pragma unroll
  for (int i = 0; i < (NSCALES * QPB) / TPB; ++i) {   // 8 iters
    const int idx = i * TPB + t;          // 0..2047
    const int sc  = idx >> 7;             // idx / QPB
    const int qi  = idx & (QPB - 1);
    const int q   = q0 + qi;
    st[sc][qi] = ws[(size_t)sc * N + (q < N ? q : N - 1)];
  }
  __syncthreads();
#pragma unroll
  for (int i = 0; i < (QPB * 8) / TPB; ++i) {         // 4 iters
    const int g  = i * TPB + t;           // 0..1023
    const int qi = g >> 3;
    const int h  = g & 7;
    const int q  = q0 + qi;
    if (q < N) {
      const float2 a = st[2 * h][qi];
      const float2 b = st[2 * h + 1][qi];
      const uint32_t pq = perm[q];
      v4f val = { a.x, a.y, b.x, b.y };
      __builtin_nontemporal_store(val, (v4f*)(out + (size_t)pq * 32 + h * 4));
    }
  }
}

// ---------------- fallback phase-2: LDS transpose (no perm) ----------------
__global__ __launch_bounds__(TPB) void transpose_kernel(
    const float2* __restrict__ ws,
    float*        __restrict__ out,
    int N)
{
  __shared__ float2 st[NSCALES][TPB + 1];
  const int t  = threadIdx.x;
  const int q  = blockIdx.x * TPB + t;
  const int ql = q < N ? q : N - 1;
#pragma unroll
  for (int s = 0; s < NSCALES; ++s)
    st[s][t] = ws[(size_t)s * N + ql];
  __syncthreads();
  const int base = blockIdx.x * (TPB * 2 * NSCALES);
#pragma unroll
  for (int it = 0; it < 8; ++it) {
    const int G  = it * 1024 + t * 4;
    const int qi = G >> 5;
    const int s0 = (G & 31) >> 1;
    if (blockIdx.x * TPB + qi < N) {
      const float2 a = st[s0][qi];
      const float2 b = st[s0 + 1][qi];
      v4f val = { a.x, a.y, b.x, b.y };
      __builtin_nontemporal_store(val, (v4f*)(out + base + G));
    }
  }
}

// ---------------- fallback: fused single-kernel (if ws tiny) ----------------
__global__ __launch_bounds__(TPB) void hashenc_fused(
    const float4* __restrict__ xyzt,
    const float*  __restrict__ table,
    float*        __restrict__ out,
    int N, Cfg cfg)
{
  __shared__ float2 st[NSCALES][TPB + 1];
  const int t  = threadIdx.x;
  const int q  = blockIdx.x * TPB + t;
  const int ql = q < N ? q : N - 1;
  const float4 c = xyzt[ql];
#pragma unroll 1
  for (int s = 0; s < NSCALES; ++s) {
    const float rx = cfg.res[s][0], ry = cfg.res[s][1];
    const float rz = cfg.res[s][2], rw = cfg.res[s][3];
    const uint32_t K0 = cfg.key[s][0], K1 = cfg.key[s][1];
    const uint32_t K2 = cfg.key[s][2], K3 = cfg.key[s][3];
    const float px = c.x * rx, py = c.y * ry, pz = c.z * rz, pw = c.w * rw;
    const float gx = floorf(px), gy = floorf(py), gz = floorf(pz), gw = floorf(pw);
    const float fx = px - gx, fy = py - gy, fz = pz - gz, fw = pw - gw;
    const uint32_t ix = (uint32_t)(int)gx, iy = (uint32_t)(int)gy;
    const uint32_t iz = (uint32_t)(int)gz, iw = (uint32_t)(int)gw;
    const uint32_t x0 = ix * K0, x1 = x0 + K0;
    const uint32_t y0 = iy * K1, y1 = y0 + K1;
    const uint32_t z0 = iz * K2, z1 = z0 + K2;
    const uint32_t u0 = iw * K3, u1 = u0 + K3;
    const float wx0 = 1.f - fx, wy0 = 1.f - fy, wz0 = 1.f - fz, ww0 = 1.f - fw;
    const float wA[4] = { wx0 * wy0, fx * wy0, wx0 * fy, fx * fy };
    const float wB[4] = { wz0 * ww0, fz * ww0, wz0 * fw, fz * fw };
    const float2* __restrict__ tb =
        reinterpret_cast<const float2*>(table + cfg.offset[s]);
    float a0 = 0.f, a1 = 0.f;
    if (cfg.dense[s]) {
      const uint32_t hA[4] = { x0 + y0, x1 + y0, x0 + y1, x1 + y1 };
      const uint32_t hB[4] = { z0 + u0, z1 + u0, z0 + u1, z1 + u1 };
#pragma unroll
      for (int i = 0; i < 16; ++i) {
        const uint32_t idx = hA[i & 3] + hB[i >> 2];
        const float2 v = tb[idx];
        const float w = wA[i & 3] * wB[i >> 2];
        a0 = fmaf(w, v.x, a0); a1 = fmaf(w, v.y, a1);
      }
    } else {
      const uint32_t msk = cfg.mask[s];
      const uint32_t hA[4] = { x0 ^ y0, x1 ^ y0, x0 ^ y1, x1 ^ y1 };
      const uint32_t hB[4] = { z0 ^ u0, z1 ^ u0, z0 ^ u1, z1 ^ u1 };
#pragma unroll
      for (int i = 0; i < 16; ++i) {
        const uint32_t idx = (hA[i & 3] ^ hB[i >> 2]) & msk;
        const float2 v = tb[idx];
        const float w = wA[i & 3] * wB[i >> 2];
        a0 = fmaf(w, v.x, a0); a1 = fmaf(w, v.y, a1);
      }
    }
    st[s][t] = make_float2(a0, a1);
  }
  __syncthreads();
  const int base = blockIdx.x * (TPB * 2 * NSCALES);
#pragma unroll
  for (int it = 0; it < 8; ++it) {
    const int G  = it * 1024 + t * 4;
    const int qi = G >> 5;
    const int s0 = (G & 31) >> 1;
    if (blockIdx.x * TPB + qi < N) {
      const float2 a = st[s0][qi];
      const float2 b = st[s0 + 1][qi];
      v4f val = { a.x, a.y, b.x, b.y };
      __builtin_nontemporal_store(val, (v4f*)(out + base + G));
    }
  }
}

// ---- host-side config, bit-exact replication of build_config() ----
static void build_cfg(Cfg& cfg)
{
  const double minr[4] = { 16.0, 16.0, 16.0, 16.0 };
  const double maxr[4] = { 256.0, 256.0, 256.0, 128.0 };
  const uint32_t primes[4] = { 1u, 2654435761u, 805459861u, 3674653429u };

  double b[4];
  for (int d = 0; d < 4; ++d)
    b[d] = ::exp((::log(maxr[d]) - ::log(minr[d])) / (double)(NSCALES - 1));

  long long total = 0;
  for (int s = 0; s < NSCALES; ++s) {
    long long res[4];
    for (int d = 0; d < 4; ++d)
      res[d] = (long long)::ceil(minr[d] * ::pow(b[d], (double)s));

    const long long raw =
        (res[0] + 1) * (res[1] + 1) * (res[2] + 1) * (res[3] + 1);
    long long p = (raw % 8 == 0) ? raw : ((raw + 7) / 8) * 8;
    if (p > 524288) p = 524288;
    const int ind = (raw <= p) ? 1 : 0;

    for (int d = 0; d < 4; ++d) cfg.res[s][d] = (float)res[d];
    if (ind) {
      cfg.key[s][0] = 1u;
      cfg.key[s][1] = (uint32_t)(res[0] + 1);
      cfg.key[s][2] = (uint32_t)((res[0] + 1) * (res[1] + 1));
      cfg.key[s][3] = (uint32_t)((res[0] + 1) * (res[1] + 1) * (res[2] + 1));
    } else {
      for (int d = 0; d < 4; ++d) cfg.key[s][d] = primes[d];
    }
    cfg.mask[s]   = (uint32_t)(p - 1);
    cfg.offset[s] = (int)total;
    cfg.dense[s]  = ind;
    total += p * 2;
  }
}

static inline size_t align_up(size_t v, size_t a) { return (v + a - 1) & ~(a - 1); }

extern "C" void kernel_launch(void* const* d_in, const int* in_sizes, int n_in,
                              void* d_out, int out_size, void* d_ws, size_t ws_size,
                              hipStream_t stream)
{
  const float* xyzt  = (const float*)d_in[0];
  const float* table = (const float*)d_in[1];
  float*       out   = (float*)d_out;
  const int N = in_sizes[0] / 4;

  Cfg cfg;
  build_cfg(cfg);

  const int qblocks = (N + TPB - 1) / TPB;

  // workspace layout (hist and cur contiguous -> single memset)
  size_t off = 0;
  const size_t perm_off = off;             off = align_up(off + (size_t)N * 4, 256);
  const size_t hist_off = off;             off += (size_t)BINS * 4;
  const size_t cur_off  = off;             off = align_up(off + (size_t)BINS * 4, 256);
  const size_t boff_off = off;             off = align_up(off + (size_t)BINS * 4, 256);
  const size_t cs_off   = align_up(off, 16);  off = cs_off + (size_t)N * 16;
  const size_t ws_off   = align_up(off, 16);
  const size_t need_sorted = ws_off + (size_t)N * NSCALES * sizeof(float2);
  const size_t need_plain  = (size_t)N * NSCALES * sizeof(float2);

  char* wsb = (char*)d_ws;

  if (ws_size >= need_sorted) {
    uint32_t* perm = (uint32_t*)(wsb + perm_off);
    uint32_t* hist = (uint32_t*)(wsb + hist_off);
    uint32_t* cur  = (uint32_t*)(wsb + cur_off);
    uint32_t* boff = (uint32_t*)(wsb + boff_off);
    float*    csrt = (float*)(wsb + cs_off);
    float2*   ws   = (float2*)(wsb + ws_off);

    hipMemsetAsync(hist, 0, (size_t)BINS * 8, stream);   // hist + cur
    hipLaunchKernelGGL(hist_kernel, dim3(qblocks), dim3(TPB), 0, stream,
                       xyzt, hist, N);
    hipLaunchKernelGGL(scan_kernel, dim3(1), dim3(1024), 0, stream, hist, boff);
    hipLaunchKernelGGL(scatter_kernel, dim3(qblocks), dim3(TPB), 0, stream,
                       xyzt, boff, cur, perm, csrt, N);
    hipLaunchKernelGGL(gather_kernel, dim3(qblocks, NSCALES), dim3(TPB), 0,
                       stream, csrt, table, ws, N, 0, cfg);
    const int tblocks = (N + QPB - 1) / QPB;
    hipLaunchKernelGGL(transpose_perm, dim3(tblocks), dim3(TPB), 0, stream,
                       ws, perm, out, N);
  } else if (ws_size >= need_plain) {
    float2* ws = (float2*)d_ws;
    hipLaunchKernelGGL(gather_kernel, dim3(qblocks, NSCALES), dim3(TPB), 0,
                       stream, xyzt, table, ws, N, 0, cfg);
    hipLaunchKernelGGL(transpose_kernel, dim3(qblocks), dim3(TPB), 0,
                       stream, ws, out, N);
  } else {
    hipLaunchKernelGGL(hashenc_fused, dim3(qblocks), dim3(TPB), 0,
                       stream, (const float4*)xyzt, table, out, N, cfg);
  }
}

// Round 5
// 809.308 us; speedup vs baseline: 1.2764x; 1.0024x over previous
//
#include <hip/hip_runtime.h>
#include <cstdint>
#include <cmath>

// HashEncoderHyFluid round 10: r8 consolidation, compile-fixed (r9 failed:
// __builtin_nontemporal_load rejects HIP_vector_type float2* -> load via
// ext_vector v2f pointer instead; same global_load_dwordx2).
// r7 A/B results: (a) MLP restructure = null (VGPR 36 unchanged -> compiler
// already batched loads; gather is L2-request-throughput bound at ~0.67
// unique lines/cyc/CU, ~1.4 cyc/line); (b) plain ws stores regressed gather
// +13us / FETCH +34MB (128MB ws write-allocate evicts the XCD-resident 4MB
// hash table) -> revert to nontemporal; (c) transpose_perm won -43us -> keep.
// This round: nontemporal ws stores restored; scan writes running cursor
// directly (scatter = single atomicAdd, no boff read, one less array+memset);
// transpose reads ws nontemporally (dying data, don't pollute L2).
// Pipeline: memset(hist) -> histogram -> scan(writes cur) -> scatter(perm,
// c_sorted) -> gather16 (sorted coords, scale-major grid) -> LDS transpose+perm.

#define NSCALES 16
#define TPB 256
#define BINS 65536
#define QPB 128   // queries per transpose block

struct Cfg {
  float    res[NSCALES][4];
  uint32_t key[NSCALES][4];
  uint32_t mask[NSCALES];
  int      offset[NSCALES];
  int      dense[NSCALES];
};

typedef float v4f __attribute__((ext_vector_type(4)));
typedef float v2f __attribute__((ext_vector_type(2)));

__device__ __forceinline__ uint32_t bucket_key(float x, float y, float z, float w)
{
  uint32_t bx = (uint32_t)(x * 16.f); bx = bx > 15u ? 15u : bx;
  uint32_t by = (uint32_t)(y * 16.f); by = by > 15u ? 15u : by;
  uint32_t bz = (uint32_t)(z * 16.f); bz = bz > 15u ? 15u : bz;
  uint32_t bt = (uint32_t)(w * 16.f); bt = bt > 15u ? 15u : bt;
  uint32_t k = 0;
#pragma unroll
  for (int b = 0; b < 4; ++b) {
    k |= ((bx >> b) & 1u) << (4 * b + 0);
    k |= ((by >> b) & 1u) << (4 * b + 1);
    k |= ((bz >> b) & 1u) << (4 * b + 2);
    k |= ((bt >> b) & 1u) << (4 * b + 3);
  }
  return k;
}

// ---------------- sort phase ----------------
__global__ __launch_bounds__(TPB) void hist_kernel(
    const float* __restrict__ xyzt, uint32_t* __restrict__ hist, int N)
{
  const int i = blockIdx.x * TPB + threadIdx.x;
  if (i >= N) return;
  const v4f c = *(reinterpret_cast<const v4f*>(xyzt) + i);
  atomicAdd(&hist[bucket_key(c.x, c.y, c.z, c.w)], 1u);
}

// exclusive scan of hist -> cur (cur then serves as the atomic cursor)
__global__ __launch_bounds__(1024) void scan_kernel(
    const uint32_t* __restrict__ hist, uint32_t* __restrict__ cur)
{
  __shared__ uint32_t part[1024];
  const int t = threadIdx.x;
  const int base = t * (BINS / 1024);
  uint32_t s = 0;
  for (int j = 0; j < BINS / 1024; ++j) s += hist[base + j];
  part[t] = s;
  __syncthreads();
  for (int off = 1; off < 1024; off <<= 1) {
    uint32_t v = (t >= off) ? part[t - off] : 0u;
    __syncthreads();
    part[t] += v;
    __syncthreads();
  }
  uint32_t run = part[t] - s;   // exclusive prefix of this chunk
  for (int j = 0; j < BINS / 1024; ++j) {
    cur[base + j] = run;
    run += hist[base + j];
  }
}

__global__ __launch_bounds__(TPB) void scatter_kernel(
    const float* __restrict__ xyzt,
    uint32_t* __restrict__ cur,
    uint32_t* __restrict__ perm, float* __restrict__ c_sorted, int N)
{
  const int i = blockIdx.x * TPB + threadIdx.x;
  if (i >= N) return;
  const v4f c = *(reinterpret_cast<const v4f*>(xyzt) + i);
  const uint32_t k = bucket_key(c.x, c.y, c.z, c.w);
  const uint32_t pos = atomicAdd(&cur[k], 1u);
  perm[pos] = (uint32_t)i;
  *(reinterpret_cast<v4f*>(c_sorted) + pos) = c;
}

// ---------------- gather: per-scale, scale = slow grid dim ----------------
__global__ __launch_bounds__(TPB) void gather_kernel(
    const float*  __restrict__ coords,
    const float*  __restrict__ table,
    float2*       __restrict__ ws,
    int N, int s_base, Cfg cfg)
{
  const int s = (int)blockIdx.y + s_base;
  const int q = blockIdx.x * TPB + threadIdx.x;
  if (q >= N) return;
  const v4f c = *(reinterpret_cast<const v4f*>(coords) + q);

  const float rx = cfg.res[s][0], ry = cfg.res[s][1];
  const float rz = cfg.res[s][2], rw = cfg.res[s][3];
  const uint32_t K0 = cfg.key[s][0], K1 = cfg.key[s][1];
  const uint32_t K2 = cfg.key[s][2], K3 = cfg.key[s][3];

  const float px = c.x * rx, py = c.y * ry, pz = c.z * rz, pw = c.w * rw;
  const float gx = floorf(px), gy = floorf(py), gz = floorf(pz), gw = floorf(pw);
  const float fx = px - gx, fy = py - gy, fz = pz - gz, fw = pw - gw;
  const uint32_t ix = (uint32_t)(int)gx, iy = (uint32_t)(int)gy;
  const uint32_t iz = (uint32_t)(int)gz, iw = (uint32_t)(int)gw;

  const uint32_t x0 = ix * K0, x1 = x0 + K0;
  const uint32_t y0 = iy * K1, y1 = y0 + K1;
  const uint32_t z0 = iz * K2, z1 = z0 + K2;
  const uint32_t u0 = iw * K3, u1 = u0 + K3;

  const float wx0 = 1.f - fx, wy0 = 1.f - fy, wz0 = 1.f - fz, ww0 = 1.f - fw;
  const float wA[4] = { wx0 * wy0, fx * wy0, wx0 * fy, fx * fy };
  const float wB[4] = { wz0 * ww0, fz * ww0, wz0 * fw, fz * fw };

  const float*  tbf = table + cfg.offset[s];
  const float2* __restrict__ tb  = reinterpret_cast<const float2*>(tbf);
  const float4* __restrict__ tb4 = reinterpret_cast<const float4*>(tbf);

  float a0 = 0.f, a1 = 0.f;
  if (cfg.dense[s]) {
    const uint32_t hA[4] = { x0 + y0, x1 + y0, x0 + y1, x1 + y1 };
    const uint32_t hB[4] = { z0 + u0, z1 + u0, z0 + u1, z1 + u1 };
#pragma unroll
    for (int i = 0; i < 16; ++i) {
      const uint32_t idx = hA[i & 3] + hB[i >> 2];
      const float2 v = tb[idx];
      const float w = wA[i & 3] * wB[i >> 2];
      a0 = fmaf(w, v.x, a0);
      a1 = fmaf(w, v.y, a1);
    }
  } else {
    const uint32_t msk = cfg.mask[s];
    if ((ix & 1u) == 0u) {
      // even ix: x-corner pair = {p, p^1} -> one aligned float4 each
      const uint32_t yv[2] = { y0, y1 };
      const uint32_t zw[4] = { z0 ^ u0, z1 ^ u0, z0 ^ u1, z1 ^ u1 };
#pragma unroll
      for (int j = 0; j < 8; ++j) {
        const int jy = j & 1, jz = j >> 1;
        const uint32_t p  = (x0 ^ yv[jy] ^ zw[jz]) & msk;
        const uint32_t e  = p & ~1u;
        const uint32_t sel = p & 1u;
        const float4 v = tb4[e >> 1];
        const float wlo = wA[2 * jy]     * wB[jz];
        const float whi = wA[2 * jy + 1] * wB[jz];
        const float l0 = sel ? v.z : v.x, l1 = sel ? v.w : v.y;
        const float h0 = sel ? v.x : v.z, h1 = sel ? v.y : v.w;
        a0 = fmaf(wlo, l0, fmaf(whi, h0, a0));
        a1 = fmaf(wlo, l1, fmaf(whi, h1, a1));
      }
    } else {
      const uint32_t hA[4] = { x0 ^ y0, x1 ^ y0, x0 ^ y1, x1 ^ y1 };
      const uint32_t hB[4] = { z0 ^ u0, z1 ^ u0, z0 ^ u1, z1 ^ u1 };
#pragma unroll
      for (int i = 0; i < 16; ++i) {
        const uint32_t idx = (hA[i & 3] ^ hB[i >> 2]) & msk;
        const float2 v = tb[idx];
        const float w = wA[i & 3] * wB[i >> 2];
        a0 = fmaf(w, v.x, a0);
        a1 = fmaf(w, v.y, a1);
      }
    }
  }
  // nontemporal: keep the 128MB ws stream out of L2 (tables must stay hot)
  v2f val = { a0, a1 };
  __builtin_nontemporal_store(val, (v2f*)&ws[(size_t)s * N + q]);
}

// ---------------- LDS transpose + perm scatter ----------------
// block = QPB sorted queries. Stage ws coalesced per scale into LDS, then
// 8 lanes emit one query's 128B output chunk (coalesced random-base write).
__global__ __launch_bounds__(TPB) void transpose_perm(
    const float2*   __restrict__ ws,
    const uint32_t* __restrict__ perm,
    float*          __restrict__ out,
    int N)
{
  __shared__ float2 st[NSCALES][QPB + 1];
  const int t  = threadIdx.x;
  const int q0 = blockIdx.x * QPB;
#pragma unroll
  for (int i = 0; i < (NSCALES * QPB) / TPB; ++i) {   // 8 iters
    const int idx = i * TPB + t;          // 0..2047
    const int sc  = idx >> 7;             // idx / QPB
    const int qi  = idx & (QPB - 1);
    const int q   = q0 + qi;
    const v2f tmp = __builtin_nontemporal_load(
        reinterpret_cast<const v2f*>(&ws[(size_t)sc * N + (q < N ? q : N - 1)]));
    st[sc][qi] = make_float2(tmp.x, tmp.y);
  }
  __syncthreads();
#pragma unroll
  for (int i = 0; i < (QPB * 8) / TPB; ++i) {         // 4 iters
    const int g  = i * TPB + t;           // 0..1023
    const int qi = g >> 3;
    const int h  = g & 7;
    const int q  = q0 + qi;
    if (q < N) {
      const float2 a = st[2 * h][qi];
      const float2 b = st[2 * h + 1][qi];
      const uint32_t pq = perm[q];
      v4f val = { a.x, a.y, b.x, b.y };
      __builtin_nontemporal_store(val, (v4f*)(out + (size_t)pq * 32 + h * 4));
    }
  }
}

// ---------------- fallback phase-2: LDS transpose (no perm) ----------------
__global__ __launch_bounds__(TPB) void transpose_kernel(
    const float2* __restrict__ ws,
    float*        __restrict__ out,
    int N)
{
  __shared__ float2 st[NSCALES][TPB + 1];
  const int t  = threadIdx.x;
  const int q  = blockIdx.x * TPB + t;
  const int ql = q < N ? q : N - 1;
#pragma unroll
  for (int s = 0; s < NSCALES; ++s)
    st[s][t] = ws[(size_t)s * N + ql];
  __syncthreads();
  const int base = blockIdx.x * (TPB * 2 * NSCALES);
#pragma unroll
  for (int it = 0; it < 8; ++it) {
    const int G  = it * 1024 + t * 4;
    const int qi = G >> 5;
    const int s0 = (G & 31) >> 1;
    if (blockIdx.x * TPB + qi < N) {
      const float2 a = st[s0][qi];
      const float2 b = st[s0 + 1][qi];
      v4f val = { a.x, a.y, b.x, b.y };
      __builtin_nontemporal_store(val, (v4f*)(out + base + G));
    }
  }
}

// ---------------- fallback: fused single-kernel (if ws tiny) ----------------
__global__ __launch_bounds__(TPB) void hashenc_fused(
    const float4* __restrict__ xyzt,
    const float*  __restrict__ table,
    float*        __restrict__ out,
    int N, Cfg cfg)
{
  __shared__ float2 st[NSCALES][TPB + 1];
  const int t  = threadIdx.x;
  const int q  = blockIdx.x * TPB + t;
  const int ql = q < N ? q : N - 1;
  const float4 c = xyzt[ql];
#pragma unroll 1
  for (int s = 0; s < NSCALES; ++s) {
    const float rx = cfg.res[s][0], ry = cfg.res[s][1];
    const float rz = cfg.res[s][2], rw = cfg.res[s][3];
    const uint32_t K0 = cfg.key[s][0], K1 = cfg.key[s][1];
    const uint32_t K2 = cfg.key[s][2], K3 = cfg.key[s][3];
    const float px = c.x * rx, py = c.y * ry, pz = c.z * rz, pw = c.w * rw;
    const float gx = floorf(px), gy = floorf(py), gz = floorf(pz), gw = floorf(pw);
    const float fx = px - gx, fy = py - gy, fz = pz - gz, fw = pw - gw;
    const uint32_t ix = (uint32_t)(int)gx, iy = (uint32_t)(int)gy;
    const uint32_t iz = (uint32_t)(int)gz, iw = (uint32_t)(int)gw;
    const uint32_t x0 = ix * K0, x1 = x0 + K0;
    const uint32_t y0 = iy * K1, y1 = y0 + K1;
    const uint32_t z0 = iz * K2, z1 = z0 + K2;
    const uint32_t u0 = iw * K3, u1 = u0 + K3;
    const float wx0 = 1.f - fx, wy0 = 1.f - fy, wz0 = 1.f - fz, ww0 = 1.f - fw;
    const float wA[4] = { wx0 * wy0, fx * wy0, wx0 * fy, fx * fy };
    const float wB[4] = { wz0 * ww0, fz * ww0, wz0 * fw, fz * fw };
    const float2* __restrict__ tb =
        reinterpret_cast<const float2*>(table + cfg.offset[s]);
    float a0 = 0.f, a1 = 0.f;
    if (cfg.dense[s]) {
      const uint32_t hA[4] = { x0 + y0, x1 + y0, x0 + y1, x1 + y1 };
      const uint32_t hB[4] = { z0 + u0, z1 + u0, z0 + u1, z1 + u1 };
#pragma unroll
      for (int i = 0; i < 16; ++i) {
        const uint32_t idx = hA[i & 3] + hB[i >> 2];
        const float2 v = tb[idx];
        const float w = wA[i & 3] * wB[i >> 2];
        a0 = fmaf(w, v.x, a0); a1 = fmaf(w, v.y, a1);
      }
    } else {
      const uint32_t msk = cfg.mask[s];
      const uint32_t hA[4] = { x0 ^ y0, x1 ^ y0, x0 ^ y1, x1 ^ y1 };
      const uint32_t hB[4] = { z0 ^ u0, z1 ^ u0, z0 ^ u1, z1 ^ u1 };
#pragma unroll
      for (int i = 0; i < 16; ++i) {
        const uint32_t idx = (hA[i & 3] ^ hB[i >> 2]) & msk;
        const float2 v = tb[idx];
        const float w = wA[i & 3] * wB[i >> 2];
        a0 = fmaf(w, v.x, a0); a1 = fmaf(w, v.y, a1);
      }
    }
    st[s][t] = make_float2(a0, a1);
  }
  __syncthreads();
  const int base = blockIdx.x * (TPB * 2 * NSCALES);
#pragma unroll
  for (int it = 0; it < 8; ++it) {
    const int G  = it * 1024 + t * 4;
    const int qi = G >> 5;
    const int s0 = (G & 31) >> 1;
    if (blockIdx.x * TPB + qi < N) {
      const float2 a = st[s0][qi];
      const float2 b = st[s0 + 1][qi];
      v4f val = { a.x, a.y, b.x, b.y };
      __builtin_nontemporal_store(val, (v4f*)(out + base + G));
    }
  }
}

// ---- host-side config, bit-exact replication of build_config() ----
static void build_cfg(Cfg& cfg)
{
  const double minr[4] = { 16.0, 16.0, 16.0, 16.0 };
  const double maxr[4] = { 256.0, 256.0, 256.0, 128.0 };
  const uint32_t primes[4] = { 1u, 2654435761u, 805459861u, 3674653429u };

  double b[4];
  for (int d = 0; d < 4; ++d)
    b[d] = ::exp((::log(maxr[d]) - ::log(minr[d])) / (double)(NSCALES - 1));

  long long total = 0;
  for (int s = 0; s < NSCALES; ++s) {
    long long res[4];
    for (int d = 0; d < 4; ++d)
      res[d] = (long long)::ceil(minr[d] * ::pow(b[d], (double)s));

    const long long raw =
        (res[0] + 1) * (res[1] + 1) * (res[2] + 1) * (res[3] + 1);
    long long p = (raw % 8 == 0) ? raw : ((raw + 7) / 8) * 8;
    if (p > 524288) p = 524288;
    const int ind = (raw <= p) ? 1 : 0;

    for (int d = 0; d < 4; ++d) cfg.res[s][d] = (float)res[d];
    if (ind) {
      cfg.key[s][0] = 1u;
      cfg.key[s][1] = (uint32_t)(res[0] + 1);
      cfg.key[s][2] = (uint32_t)((res[0] + 1) * (res[1] + 1));
      cfg.key[s][3] = (uint32_t)((res[0] + 1) * (res[1] + 1) * (res[2] + 1));
    } else {
      for (int d = 0; d < 4; ++d) cfg.key[s][d] = primes[d];
    }
    cfg.mask[s]   = (uint32_t)(p - 1);
    cfg.offset[s] = (int)total;
    cfg.dense[s]  = ind;
    total += p * 2;
  }
}

static inline size_t align_up(size_t v, size_t a) { return (v + a - 1) & ~(a - 1); }

extern "C" void kernel_launch(void* const* d_in, const int* in_sizes, int n_in,
                              void* d_out, int out_size, void* d_ws, size_t ws_size,
                              hipStream_t stream)
{
  const float* xyzt  = (const float*)d_in[0];
  const float* table = (const float*)d_in[1];
  float*       out   = (float*)d_out;
  const int N = in_sizes[0] / 4;

  Cfg cfg;
  build_cfg(cfg);

  const int qblocks = (N + TPB - 1) / TPB;

  // workspace layout
  size_t off = 0;
  const size_t perm_off = off;             off = align_up(off + (size_t)N * 4, 256);
  const size_t hist_off = off;             off = align_up(off + (size_t)BINS * 4, 256);
  const size_t cur_off  = off;             off = align_up(off + (size_t)BINS * 4, 256);
  const size_t cs_off   = align_up(off, 16);  off = cs_off + (size_t)N * 16;
  const size_t ws_off   = align_up(off, 16);
  const size_t need_sorted = ws_off + (size_t)N * NSCALES * sizeof(float2);
  const size_t need_plain  = (size_t)N * NSCALES * sizeof(float2);

  char* wsb = (char*)d_ws;

  if (ws_size >= need_sorted) {
    uint32_t* perm = (uint32_t*)(wsb + perm_off);
    uint32_t* hist = (uint32_t*)(wsb + hist_off);
    uint32_t* cur  = (uint32_t*)(wsb + cur_off);
    float*    csrt = (float*)(wsb + cs_off);
    float2*   ws   = (float2*)(wsb + ws_off);

    hipMemsetAsync(hist, 0, (size_t)BINS * 4, stream);
    hipLaunchKernelGGL(hist_kernel, dim3(qblocks), dim3(TPB), 0, stream,
                       xyzt, hist, N);
    hipLaunchKernelGGL(scan_kernel, dim3(1), dim3(1024), 0, stream, hist, cur);
    hipLaunchKernelGGL(scatter_kernel, dim3(qblocks), dim3(TPB), 0, stream,
                       xyzt, cur, perm, csrt, N);
    hipLaunchKernelGGL(gather_kernel, dim3(qblocks, NSCALES), dim3(TPB), 0,
                       stream, csrt, table, ws, N, 0, cfg);
    const int tblocks = (N + QPB - 1) / QPB;
    hipLaunchKernelGGL(transpose_perm, dim3(tblocks), dim3(TPB), 0, stream,
                       ws, perm, out, N);
  } else if (ws_size >= need_plain) {
    float2* ws = (float2*)d_ws;
    hipLaunchKernelGGL(gather_kernel, dim3(qblocks, NSCALES), dim3(TPB), 0,
                       stream, xyzt, table, ws, N, 0, cfg);
    hipLaunchKernelGGL(transpose_kernel, dim3(qblocks), dim3(TPB), 0,
                       stream, ws, out, N);
  } else {
    hipLaunchKernelGGL(hashenc_fused, dim3(qblocks), dim3(TPB), 0,
                       stream, (const float4*)xyzt, table, out, N, cfg);
  }
}